// Round 5
// baseline (127.930 us; speedup 1.0000x reference)
//
#include <hip/hip_runtime.h>

// Problem constants (fixed by setup_inputs): B=4, C=32, H=W=256, heads=4, amp=2.
#define Bdim 4
#define Cdim 32
#define NH   4
#define HD   8      // head_dim = C / NH
#define Hdim 256
#define Wdim 256
#define AMP  2
#define KS   5      // 2*AMP+1

// Tile per block: 32 px wide x 8 rows, ONE head (channels d*4+h, d=0..7).
#define XT    32
#define TY    8
#define TROWS (TY + 2*AMP)          // 12
#define TCOLS 44                    // 40 used + 4 pad (44%32=12 -> clean banks)
#define CH_STRIDE (TROWS * TCOLS)   // 528 floats
#define TILE_F (HD * CH_STRIDE)     // 4224 floats = 16.5 KiB

__global__ __launch_bounds__(64) void natt_head_kernel(
    const float* __restrict__ xq,
    const float* __restrict__ xk,
    float* __restrict__ part)       // [NH][B][2][H][W] partial head results
{
    __shared__ float kt[TILE_F];

    const int lane = threadIdx.x;   // 0..63
    const int bid  = blockIdx.x;    // 0..4095

    // XCD swizzle: bid%8 = XCD; each XCD owns a contiguous 32-row y-slab.
    const int xcd = bid & 7;
    const int u   = bid >> 3;       // 0..511
    const int yt  = xcd * 4 + (u & 3);   // 0..31
    const int v   = u >> 2;         // 0..127
    const int xt  = v & 7;          // 0..7
    const int w2  = v >> 3;         // 0..15
    const int h   = w2 & 3;         // head
    const int b   = w2 >> 2;        // batch

    const int Y0 = yt * TY;
    const int X0 = xt * XT;

    const int row = lane >> 3;      // 0..7
    const int qx  = lane & 7;       // 0..7 (4 px each)
    const int y   = Y0 + row;
    const int x0  = X0 + qx * 4;

    const size_t plane = (size_t)Hdim * Wdim;
    const float scale = 0.35355339059327373f;   // 8^-0.5

    // ---- stage this head's 8 channels: rows Y0-2..Y0+9, cols X0-4..X0+35.
    // Clamped loads: out-of-image slots hold finite garbage, only ever read
    // by taps the validity predicate zeroes.
    {
        const float* kb = xk + (size_t)b * Cdim * plane;
        #pragma unroll
        for (int it = 0; it < 15; ++it) {       // 8*12*10 = 960 float4 jobs
            const int i  = lane + it * 64;
            const int q4 = i % 10;
            const int t  = i / 10;
            const int rw = t % 12;
            const int l  = t / 12;              // local channel 0..7
            int yr = Y0 - AMP + rw;
            yr = yr < 0 ? 0 : (yr > Hdim - 1 ? Hdim - 1 : yr);
            int xc = X0 - 4 + q4 * 4;
            xc = xc < 0 ? 0 : (xc > Wdim - 4 ? Wdim - 4 : xc);
            const float4 kv = *(const float4*)(kb + (size_t)(l * NH + h) * plane
                                               + (size_t)yr * Wdim + xc);
            *(float4*)(kt + l * CH_STRIDE + rw * TCOLS + q4 * 4) = kv;
        }
    }

    // ---- q fragments (channels c = d*NH + h), 4 px each
    const float* qb = xq + (size_t)b * Cdim * plane + (size_t)y * Wdim + x0;
    float q[HD][4];
    #pragma unroll
    for (int d = 0; d < HD; ++d) {
        const float4 qv = *(const float4*)(qb + (size_t)(d * NH + h) * plane);
        q[d][0] = qv.x * scale; q[d][1] = qv.y * scale;
        q[d][2] = qv.z * scale; q[d][3] = qv.w * scale;
    }

    __syncthreads();   // single-wave block: compiles to waitcnt + cheap barrier

    float Z[4]  = {0.f, 0.f, 0.f, 0.f};
    float sx[4] = {0.f, 0.f, 0.f, 0.f};
    float sy[4] = {0.f, 0.f, 0.f, 0.f};

    const float* ktb = kt + (size_t)row * TCOLS + qx * 4;

    #pragma unroll
    for (int r = 0; r < KS; ++r) {          // tap row
        float dot[KS][4];
        #pragma unroll
        for (int dj = 0; dj < KS; ++dj) {
            dot[dj][0] = 0.f; dot[dj][1] = 0.f; dot[dj][2] = 0.f; dot[dj][3] = 0.f;
        }

        #pragma unroll
        for (int d = 0; d < HD; ++d) {
            const float* wp = ktb + d * CH_STRIDE + r * TCOLS;
            const float4 w0 = *(const float4*)(wp);
            const float4 w1 = *(const float4*)(wp + 4);
            const float4 w2v = *(const float4*)(wp + 8);
            const float w[12] = {w0.x, w0.y, w0.z, w0.w,
                                 w1.x, w1.y, w1.z, w1.w,
                                 w2v.x, w2v.y, w2v.z, w2v.w};
            // w[k] is x = x0 + k - 4; tap (dj,p) reads x0+p+dj-2 -> w[p+dj+2]
            #pragma unroll
            for (int dj = 0; dj < KS; ++dj) {
                #pragma unroll
                for (int p = 0; p < 4; ++p)
                    dot[dj][p] += q[d][p] * w[p + dj + 2];
            }
        }

        const int yy = y + r - AMP;
        const bool rowok = (yy >= 0) && (yy < Hdim);
        const float fdi = (float)(r - AMP);
        #pragma unroll
        for (int dj = 0; dj < KS; ++dj) {
            const float fdj = (float)(dj - AMP);
            #pragma unroll
            for (int p = 0; p < 4; ++p) {
                const int xx = x0 + p + dj - AMP;
                const bool ok = rowok && (xx >= 0) && (xx < Wdim);
                const float e = ok ? __expf(dot[dj][p]) : 0.f;  // |dot|<~10, safe
                Z[p]  += e;
                sx[p] += e * fdi;
                sy[p] += e * fdj;
            }
        }
    }

    // ---- per-head partials -> workspace: part[((h*B + b)*2 + c)*plane + pix]
    const float i0 = 1.f / Z[0], i1 = 1.f / Z[1], i2 = 1.f / Z[2], i3 = 1.f / Z[3];
    const size_t pbase = (size_t)((h * Bdim + b) * 2) * plane + (size_t)y * Wdim + x0;
    *(float4*)(part + pbase)         = make_float4(sx[0]*i0, sx[1]*i1, sx[2]*i2, sx[3]*i3);
    *(float4*)(part + pbase + plane) = make_float4(sy[0]*i0, sy[1]*i1, sy[2]*i2, sy[3]*i3);
}

// Mean over heads: out[g*plane + pix] = 0.25 * sum_h part[(h*8 + g)*plane + pix],
// where g = b*2 + c (matches (B,2,H,W) output layout).
__global__ __launch_bounds__(256) void head_mean_kernel(
    const float* __restrict__ part,
    float* __restrict__ out)
{
    const int idx = blockIdx.x * 256 + threadIdx.x;   // over 8*65536/4 float4s
    const int pq  = (int)(((size_t)Hdim * Wdim) / 4); // 16384 float4 per plane
    const int g   = idx / pq;                          // 0..7
    const int r   = idx % pq;
    const float4* p4 = (const float4*)part;
    float4 a = p4[(0 * 8 + g) * pq + r];
    const float4 b1 = p4[(1 * 8 + g) * pq + r];
    const float4 b2 = p4[(2 * 8 + g) * pq + r];
    const float4 b3 = p4[(3 * 8 + g) * pq + r];
    a.x = (a.x + b1.x + b2.x + b3.x) * 0.25f;
    a.y = (a.y + b1.y + b2.y + b3.y) * 0.25f;
    a.z = (a.z + b1.z + b2.z + b3.z) * 0.25f;
    a.w = (a.w + b1.w + b2.w + b3.w) * 0.25f;
    ((float4*)out)[idx] = a;
}

extern "C" void kernel_launch(void* const* d_in, const int* in_sizes, int n_in,
                              void* d_out, int out_size, void* d_ws, size_t ws_size,
                              hipStream_t stream) {
    const float* xq = (const float*)d_in[0];
    const float* xk = (const float*)d_in[1];
    float* out  = (float*)d_out;
    float* part = (float*)d_ws;   // needs 4*4*2*65536*4 = 8.4 MB

    // 32 y-tiles x 8 x-tiles x 4 heads x 4 batches = 4096 single-wave blocks
    natt_head_kernel<<<dim3(4096, 1, 1), dim3(64, 1, 1), 0, stream>>>(xq, xk, part);
    // 2*4*65536 out floats / 4 per thread / 256 per block = 512 blocks
    head_mean_kernel<<<dim3(512, 1, 1), dim3(256, 1, 1), 0, stream>>>(part, out);
}